// Round 1
// baseline (254.743 us; speedup 1.0000x reference)
//
#include <hip/hip_runtime.h>

// ExtendedKalmanFilter: T=64, B=32768, D=6, O=3, U=6.
//
// KEY STRUCTURAL FACT: cov0 is broadcast(0.1*I) -- identical for all batch
// elements -- and A, Bm, Q, C, R are shared. Therefore the covariance /
// Kalman-gain recursion is identical for every batch element. We compute it
// ONCE (kernel 1, single workgroup) and store per-step affine coefficients:
//   mean_{t+1} = M_t mean_t + N_t u_t + K_t z_t
//   M_t = (I - K_t C) A   (6x6), N_t = (I - K_t C) Bm (6x6), K_t (6x3)
// Kernel 2 then runs the cheap affine recurrence per batch element
// (memory-bound: ~125 MB of z/u/out traffic).

#define T_STEPS 64
#define BATCH   32768
#define NCOEF   90   // per-step: M(36) + N(36) + K(18)

__global__ __launch_bounds__(64) void ekf_precompute(
    const float* __restrict__ cov0, const float* __restrict__ Ag,
    const float* __restrict__ Bg,   const float* __restrict__ Qtg,
    const float* __restrict__ Cg,   const float* __restrict__ Rtg,
    float* __restrict__ coef)
{
    __shared__ float sA[36], sB[36], sC[18], Qc[36], Rc[9];
    __shared__ float Pb[2][36], P1[36], PCt[18], S[9], iS[9], IKC[36], Kk[18];
    const int tid = threadIdx.x;

    if (tid < 36) { sA[tid] = Ag[tid]; sB[tid] = Bg[tid]; Pb[0][tid] = cov0[tid]; }
    if (tid < 18) sC[tid] = Cg[tid];
    __syncthreads();

    // Qc = Q_tril Q_tril^T ; Rc = R_tril R_tril^T
    if (tid < 36) {
        int i = tid / 6, j = tid % 6; float s = 0.f;
        for (int k = 0; k < 6; ++k) s += Qtg[i*6+k] * Qtg[j*6+k];
        Qc[tid] = s;
    } else if (tid < 45) {
        int q = tid - 36; int i = q / 3, j = q % 3; float s = 0.f;
        for (int k = 0; k < 3; ++k) s += Rtg[i*3+k] * Rtg[j*3+k];
        Rc[q] = s;
    }
    __syncthreads();

    const int i6 = tid / 6, j6 = tid % 6;
    const int i3 = tid / 3, j3 = tid % 3;

    for (int t = 0; t < T_STEPS; ++t) {
        const float* P  = Pb[t & 1];
        float*       Pn = Pb[(t & 1) ^ 1];

        // P1 = A P A^T + Qc  (lane = one output element; 42 FMA)
        if (tid < 36) {
            float s = Qc[tid];
            for (int k = 0; k < 6; ++k) {
                float tmp = 0.f;
                for (int l = 0; l < 6; ++l) tmp += P[k*6+l] * sA[j6*6+l];
                s += sA[i6*6+k] * tmp;
            }
            P1[tid] = s;
        }
        __syncthreads();

        // PCt = P1 C^T (6x3, lanes 0..17) ; S = C P1 C^T + Rc (3x3, lanes 36..44)
        if (tid < 18) {
            float s = 0.f;
            for (int k = 0; k < 6; ++k) s += P1[i3*6+k] * sC[j3*6+k];
            PCt[tid] = s;
        } else if (tid >= 36 && tid < 45) {
            int q = tid - 36; int i = q / 3, j = q % 3;
            float s = Rc[q];
            for (int k = 0; k < 6; ++k) {
                float tmp = 0.f;
                for (int l = 0; l < 6; ++l) tmp += P1[k*6+l] * sC[j*6+l];
                s += sC[i*6+k] * tmp;
            }
            S[q] = s;
        }
        __syncthreads();

        // iS = inv(S) via adjugate (3x3, well-conditioned here)
        if (tid < 9) {
            float a=S[0],b=S[1],c=S[2],d=S[3],e=S[4],f=S[5],g=S[6],h=S[7],i9=S[8];
            float det  = a*(e*i9-f*h) - b*(d*i9-f*g) + c*(d*h-e*g);
            float idet = 1.0f / det;
            float co[9];
            co[0] =  (e*i9-f*h); co[1] = -(b*i9-c*h); co[2] =  (b*f-c*e);
            co[3] = -(d*i9-f*g); co[4] =  (a*i9-c*g); co[5] = -(a*f-c*d);
            co[6] =  (d*h-e*g);  co[7] = -(a*h-b*g);  co[8] =  (a*e-b*d);
            iS[tid] = co[tid] * idet;
        }
        __syncthreads();

        // IKC = I - K C (lanes 0..35, K rows recomputed inline to save a sync)
        // K   = PCt iS  (lanes 36..53, for the coefficient store)
        if (tid < 36) {
            float s = (i6 == j6) ? 1.f : 0.f;
            for (int k = 0; k < 3; ++k) {
                float kv = 0.f;
                for (int m = 0; m < 3; ++m) kv += PCt[i6*3+m] * iS[m*3+k];
                s -= kv * sC[k*6+j6];
            }
            IKC[tid] = s;
        } else if (tid < 54) {
            int q = tid - 36; int i = q / 3, j = q % 3;
            float s = 0.f;
            for (int m = 0; m < 3; ++m) s += PCt[i*3+m] * iS[m*3+j];
            Kk[q] = s;
        }
        __syncthreads();

        // M = IKC A, N = IKC Bm, P_next = IKC P1 ; store M,N,K
        if (tid < 36) {
            float m = 0.f, n = 0.f, p = 0.f;
            for (int k = 0; k < 6; ++k) {
                float w = IKC[i6*6+k];
                m += w * sA[k*6+j6];
                n += w * sB[k*6+j6];
                p += w * P1[k*6+j6];
            }
            coef[t*NCOEF + tid]      = m;
            coef[t*NCOEF + 36 + tid] = n;
            Pn[tid] = p;
        } else if (tid < 54) {
            coef[t*NCOEF + 72 + (tid - 36)] = Kk[tid - 36];
        }
        __syncthreads();
    }
}

__global__ __launch_bounds__(128) void ekf_mean(
    const float* __restrict__ z, const float* __restrict__ u,
    const float* __restrict__ mean0, const float* __restrict__ coef,
    float* __restrict__ out)
{
    __shared__ float sc[T_STEPS * NCOEF];  // 23040 B
    const int tid = threadIdx.x;
    for (int idx = tid; idx < T_STEPS * NCOEF; idx += 128) sc[idx] = coef[idx];

    const int b = blockIdx.x * 128 + tid;
    float m[6];
    {
        const float2* mp = (const float2*)(mean0 + b * 6);
        float2 a0 = mp[0], a1 = mp[1], a2 = mp[2];
        m[0]=a0.x; m[1]=a0.y; m[2]=a1.x; m[3]=a1.y; m[4]=a2.x; m[5]=a2.y;
    }
    __syncthreads();

    #pragma unroll 2
    for (int t = 0; t < T_STEPS; ++t) {
        const float* cf  = &sc[t * NCOEF];
        const int base   = t * BATCH + b;
        const float*  zp = z + base * 3;
        const float2* up = (const float2*)(u + (size_t)base * 6);

        float zz[3] = { zp[0], zp[1], zp[2] };
        float2 u01 = up[0], u23 = up[1], u45 = up[2];
        float uu[6] = { u01.x, u01.y, u23.x, u23.y, u45.x, u45.y };

        float nm[6];
        #pragma unroll
        for (int i = 0; i < 6; ++i) {
            float s = 0.f;
            #pragma unroll
            for (int j = 0; j < 6; ++j) s += cf[i*6+j] * m[j];
            #pragma unroll
            for (int j = 0; j < 6; ++j) s += cf[36 + i*6 + j] * uu[j];
            #pragma unroll
            for (int j = 0; j < 3; ++j) s += cf[72 + i*3 + j] * zz[j];
            nm[i] = s;
        }

        float2* op = (float2*)(out + (size_t)base * 6);
        op[0] = make_float2(nm[0], nm[1]);
        op[1] = make_float2(nm[2], nm[3]);
        op[2] = make_float2(nm[4], nm[5]);

        #pragma unroll
        for (int i = 0; i < 6; ++i) m[i] = nm[i];
    }
}

extern "C" void kernel_launch(void* const* d_in, const int* in_sizes, int n_in,
                              void* d_out, int out_size, void* d_ws, size_t ws_size,
                              hipStream_t stream) {
    const float* meas  = (const float*)d_in[0];
    const float* useq  = (const float*)d_in[1];
    const float* mean0 = (const float*)d_in[2];
    const float* cov0  = (const float*)d_in[3];
    const float* A     = (const float*)d_in[4];
    const float* Bm    = (const float*)d_in[5];
    const float* Qt    = (const float*)d_in[6];
    const float* C     = (const float*)d_in[7];
    const float* Rt    = (const float*)d_in[8];
    float* out  = (float*)d_out;
    float* coef = (float*)d_ws;   // 64 * 90 * 4 = 23040 B

    ekf_precompute<<<1, 64, 0, stream>>>(cov0, A, Bm, Qt, C, Rt, coef);
    ekf_mean<<<BATCH / 128, 128, 0, stream>>>(meas, useq, mean0, coef, out);
}

// Round 3
// 229.835 us; speedup vs baseline: 1.1084x; 1.1084x over previous
//
#include <hip/hip_runtime.h>

// ExtendedKalmanFilter: T=64, B=32768, D=6, O=3, U=6.
//
// cov0 is broadcast(0.1*I) and A,Bm,Q,C,R are shared => covariance/gain
// recursion is batch-independent. Kernel 1 (1 wave) runs it once, storing
// per-step affine coefficients:  mean_{t+1} = M_t mean_t + N_t u_t + K_t z_t.
// Kernel 2 runs the affine recurrence per batch element (memory-bound).
//
// Round-3 discipline: precompute uses ROUND-1's exact formulas and
// accumulation order (proven: absmax 0.0625); only the data movement changed
// (static operands hoisted to registers, P/P1 read as float4, 5 stages
// merged to 3 with per-lane redundant S-inverse). Mean kernel is round-1
// verbatim.

#define T_STEPS 64
#define BATCH   32768
#define NCOEF   90   // per-step: M(36) + N(36) + K(18)

__global__ __launch_bounds__(64) void ekf_precompute(
    const float* __restrict__ cov0, const float* __restrict__ Ag,
    const float* __restrict__ Bg,   const float* __restrict__ Qtg,
    const float* __restrict__ Cg,   const float* __restrict__ Rtg,
    float* __restrict__ coef)
{
    __shared__ alignas(16) float sP[36];   // posterior covariance
    __shared__ alignas(16) float P1[36];   // predicted covariance
    __shared__ float sA[36], sB[36], sC[18], sQt[36], sRt[9];
    __shared__ float Qc[36], Rc[9], PCt[18], S[9];
    const int tid = threadIdx.x;

    // ---- phase 0: load params ----
    if (tid < 36) { sA[tid] = Ag[tid]; sB[tid] = Bg[tid]; sQt[tid] = Qtg[tid]; sP[tid] = cov0[tid]; }
    if (tid < 18) sC[tid] = Cg[tid];
    if (tid < 9)  sRt[tid] = Rtg[tid];
    __syncthreads();

    // ---- phase 1: Qc = Qt Qt^T, Rc = Rt Rt^T (identical to round 1) ----
    if (tid < 36) {
        int i = tid / 6, j = tid % 6; float s = 0.f;
        #pragma unroll
        for (int k = 0; k < 6; ++k) s += sQt[i*6+k] * sQt[j*6+k];
        Qc[tid] = s;
    } else if (tid < 45) {
        int q = tid - 36, i = q / 3, j = q % 3; float s = 0.f;
        #pragma unroll
        for (int k = 0; k < 3; ++k) s += sRt[i*3+k] * sRt[j*3+k];
        Rc[q] = s;
    }
    __syncthreads();

    // ---- hoist static operands into registers (reads only phase-0/1 data) ----
    const int i6 = tid / 6, j6 = tid % 6;   // meaningful for tid < 36
    const int i3 = tid / 3, j3 = tid % 3;   // meaningful for tid < 18
    float Ai[6], Aj[6], Acol[6], Bcol[6], Cst[18], Crow[6], Ca[6], Cb[6];
    float qcv = 0.f, rcv = 0.f;
    if (tid < 36) {
        #pragma unroll
        for (int l = 0; l < 6; ++l) {
            Ai[l] = sA[i6*6+l]; Aj[l] = sA[j6*6+l];
            Acol[l] = sA[l*6+j6]; Bcol[l] = sB[l*6+j6];
        }
        #pragma unroll
        for (int l = 0; l < 18; ++l) Cst[l] = sC[l];
        qcv = Qc[tid];
    }
    if (tid < 18) {
        #pragma unroll
        for (int l = 0; l < 6; ++l) Crow[l] = sC[j3*6+l];
    }
    if (tid >= 36 && tid < 45) {
        int q = tid - 36, a = q / 3, b = q % 3;
        #pragma unroll
        for (int l = 0; l < 6; ++l) { Ca[l] = sC[a*6+l]; Cb[l] = sC[b*6+l]; }
        rcv = Rc[q];
    }
    // no shared writes since last barrier -> no extra sync needed

    for (int t = 0; t < T_STEPS; ++t) {
        // ---- stage A: P1 = A P A^T + Qc  (round-1 accumulation order) ----
        if (tid < 36) {
            const float4* P4 = (const float4*)sP;
            float4 q0=P4[0],q1=P4[1],q2=P4[2],q3=P4[3],q4=P4[4],
                   q5=P4[5],q6=P4[6],q7=P4[7],q8=P4[8];
            float Pf[36] = { q0.x,q0.y,q0.z,q0.w, q1.x,q1.y,q1.z,q1.w,
                             q2.x,q2.y,q2.z,q2.w, q3.x,q3.y,q3.z,q3.w,
                             q4.x,q4.y,q4.z,q4.w, q5.x,q5.y,q5.z,q5.w,
                             q6.x,q6.y,q6.z,q6.w, q7.x,q7.y,q7.z,q7.w,
                             q8.x,q8.y,q8.z,q8.w };
            float s = qcv;
            #pragma unroll
            for (int k = 0; k < 6; ++k) {
                float tmp = 0.f;
                #pragma unroll
                for (int l = 0; l < 6; ++l) tmp += Pf[k*6+l] * Aj[l];
                s += Ai[k] * tmp;
            }
            P1[tid] = s;
        }
        __syncthreads();

        // ---- stage B: PCt = P1 C^T (lanes 0..17); S = C P1 C^T + Rc (36..44) ----
        if (tid < 18) {
            const float2* R2 = (const float2*)(P1 + i3 * 6);   // i3*6 even -> 8B aligned
            float2 r0 = R2[0], r1 = R2[1], r2 = R2[2];
            float s = r0.x*Crow[0] + r0.y*Crow[1] + r1.x*Crow[2]
                    + r1.y*Crow[3] + r2.x*Crow[4] + r2.y*Crow[5];
            PCt[tid] = s;
        } else if (tid >= 36 && tid < 45) {
            const float4* P4 = (const float4*)P1;
            float4 q0=P4[0],q1=P4[1],q2=P4[2],q3=P4[3],q4=P4[4],
                   q5=P4[5],q6=P4[6],q7=P4[7],q8=P4[8];
            float Pf[36] = { q0.x,q0.y,q0.z,q0.w, q1.x,q1.y,q1.z,q1.w,
                             q2.x,q2.y,q2.z,q2.w, q3.x,q3.y,q3.z,q3.w,
                             q4.x,q4.y,q4.z,q4.w, q5.x,q5.y,q5.z,q5.w,
                             q6.x,q6.y,q6.z,q6.w, q7.x,q7.y,q7.z,q7.w,
                             q8.x,q8.y,q8.z,q8.w };
            float s = rcv;
            #pragma unroll
            for (int l = 0; l < 6; ++l) {
                float tmp = 0.f;
                #pragma unroll
                for (int m = 0; m < 6; ++m) tmp += Pf[l*6+m] * Cb[m];
                s += Ca[l] * tmp;
            }
            S[tid - 36] = s;
        }
        __syncthreads();

        // ---- stage C: per-lane inv(S), K row, IKC row; M, N, Pnext, stores ----
        if (tid < 36) {
            float a = S[0], b = S[1], c = S[2], d = S[3], e = S[4],
                  f = S[5], g = S[6], h = S[7], i9 = S[8];
            float idet = 1.0f / (a*(e*i9-f*h) - b*(d*i9-f*g) + c*(d*h-e*g));
            float s0 =  (e*i9-f*h)*idet, s1 = -(b*i9-c*h)*idet, s2 =  (b*f-c*e)*idet;
            float s3 = -(d*i9-f*g)*idet, s4 =  (a*i9-c*g)*idet, s5 = -(a*f-c*d)*idet;
            float s6 =  (d*h-e*g)*idet,  s7 = -(a*h-b*g)*idet,  s8 =  (a*e-b*d)*idet;

            float Pi0 = PCt[i6*3+0], Pi1 = PCt[i6*3+1], Pi2 = PCt[i6*3+2];
            float K0 = Pi0*s0 + Pi1*s3 + Pi2*s6;
            float K1 = Pi0*s1 + Pi1*s4 + Pi2*s7;
            float K2 = Pi0*s2 + Pi1*s5 + Pi2*s8;

            // IKC row i6 (round-1 values, computed locally)
            float ik[6];
            #pragma unroll
            for (int k = 0; k < 6; ++k)
                ik[k] = ((i6 == k) ? 1.f : 0.f)
                      - (K0*Cst[0*6+k] + K1*Cst[1*6+k] + K2*Cst[2*6+k]);

            float mo = 0.f, no = 0.f, pn = 0.f;
            #pragma unroll
            for (int k = 0; k < 6; ++k) {
                mo += ik[k] * Acol[k];
                no += ik[k] * Bcol[k];
                pn += ik[k] * P1[k*6+j6];
            }

            coef[t*NCOEF + tid]      = mo;
            coef[t*NCOEF + 36 + tid] = no;
            if (j6 < 3)
                coef[t*NCOEF + 72 + i6*3 + j6] = (j6 == 0 ? K0 : (j6 == 1 ? K1 : K2));
            sP[tid] = pn;
        }
        __syncthreads();
    }
}

// ---- round-1 mean kernel, VERBATIM ----
__global__ __launch_bounds__(128) void ekf_mean(
    const float* __restrict__ z, const float* __restrict__ u,
    const float* __restrict__ mean0, const float* __restrict__ coef,
    float* __restrict__ out)
{
    __shared__ float sc[T_STEPS * NCOEF];  // 23040 B
    const int tid = threadIdx.x;
    for (int idx = tid; idx < T_STEPS * NCOEF; idx += 128) sc[idx] = coef[idx];

    const int b = blockIdx.x * 128 + tid;
    float m[6];
    {
        const float2* mp = (const float2*)(mean0 + b * 6);
        float2 a0 = mp[0], a1 = mp[1], a2 = mp[2];
        m[0]=a0.x; m[1]=a0.y; m[2]=a1.x; m[3]=a1.y; m[4]=a2.x; m[5]=a2.y;
    }
    __syncthreads();

    #pragma unroll 2
    for (int t = 0; t < T_STEPS; ++t) {
        const float* cf  = &sc[t * NCOEF];
        const int base   = t * BATCH + b;
        const float*  zp = z + base * 3;
        const float2* up = (const float2*)(u + (size_t)base * 6);

        float zz[3] = { zp[0], zp[1], zp[2] };
        float2 u01 = up[0], u23 = up[1], u45 = up[2];
        float uu[6] = { u01.x, u01.y, u23.x, u23.y, u45.x, u45.y };

        float nm[6];
        #pragma unroll
        for (int i = 0; i < 6; ++i) {
            float s = 0.f;
            #pragma unroll
            for (int j = 0; j < 6; ++j) s += cf[i*6+j] * m[j];
            #pragma unroll
            for (int j = 0; j < 6; ++j) s += cf[36 + i*6 + j] * uu[j];
            #pragma unroll
            for (int j = 0; j < 3; ++j) s += cf[72 + i*3 + j] * zz[j];
            nm[i] = s;
        }

        float2* op = (float2*)(out + (size_t)base * 6);
        op[0] = make_float2(nm[0], nm[1]);
        op[1] = make_float2(nm[2], nm[3]);
        op[2] = make_float2(nm[4], nm[5]);

        #pragma unroll
        for (int i = 0; i < 6; ++i) m[i] = nm[i];
    }
}

extern "C" void kernel_launch(void* const* d_in, const int* in_sizes, int n_in,
                              void* d_out, int out_size, void* d_ws, size_t ws_size,
                              hipStream_t stream) {
    const float* meas  = (const float*)d_in[0];
    const float* useq  = (const float*)d_in[1];
    const float* mean0 = (const float*)d_in[2];
    const float* cov0  = (const float*)d_in[3];
    const float* A     = (const float*)d_in[4];
    const float* Bm    = (const float*)d_in[5];
    const float* Qt    = (const float*)d_in[6];
    const float* C     = (const float*)d_in[7];
    const float* Rt    = (const float*)d_in[8];
    float* out  = (float*)d_out;
    float* coef = (float*)d_ws;   // 64 * 90 * 4 = 23040 B

    ekf_precompute<<<1, 64, 0, stream>>>(cov0, A, Bm, Qt, C, Rt, coef);
    ekf_mean<<<BATCH / 128, 128, 0, stream>>>(meas, useq, mean0, coef, out);
}

// Round 4
// 204.751 us; speedup vs baseline: 1.2442x; 1.1225x over previous
//
#include <hip/hip_runtime.h>

// ExtendedKalmanFilter: T=64, B=32768, D=6, O=3, U=6.
//
// cov0 is broadcast(0.1*I) and A,Bm,Q,C,R are shared => covariance/gain
// recursion is batch-independent. Kernel 1 (1 block) runs it once, storing
// per-step affine coefficients  mean_{t+1} = M_t mean_t + N_t u_t + K_t z_t,
// plus chunk-composed transitions G_c = M_{c*8+7}...M_{c*8}.
//
// The mean recurrence is LINEAR, so it is solved as a chunked scan (8 chunks
// of 8 steps) for 8x wave parallelism (round-3's one-thread-per-b version was
// latency-bound at 2 waves/CU, 74us vs a 14us HBM floor):
//   pass 1 (ekf_gpass): chunk offset g_c[b] = chunk replay from m=0
//   pass 2 (ekf_opass): scan boundaries bm_c = G*bm + g, replay chunk, write.
// Coefficient reads use uniform global addresses -> s_load (scalar pipe),
// eliminating per-step LDS issue cost. Inner-step arithmetic is round-1
// verbatim (proven absmax 0.0625); only chunk-boundary composition
// reassociates (contractive filter -> negligible).
//
// Fallback: if ws_size can't hold g (6.3 MB), use the proven round-3 path.

#define T_STEPS 64
#define BATCH   32768
#define NCOEF   90   // per-step: M(36) + N(36) + K(18)
#define NCHUNK  8
#define CLEN    8

#define G_OFF   23040                      // bytes: after coef[64*90]
#define GV_OFF  24192                      // bytes: after Gmat[8*36]
#define WS_NEED (GV_OFF + NCHUNK * BATCH * 6 * 4)

__global__ __launch_bounds__(512) void ekf_precompute(
    const float* __restrict__ cov0, const float* __restrict__ Ag,
    const float* __restrict__ Bg,   const float* __restrict__ Qtg,
    const float* __restrict__ Cg,   const float* __restrict__ Rtg,
    float* __restrict__ coef, float* __restrict__ Gmat, int writeG)
{
    __shared__ alignas(16) float sP[36];   // posterior covariance
    __shared__ alignas(16) float P1[36];   // predicted covariance
    __shared__ float sA[36], sB[36], sC[18], sQt[36], sRt[9];
    __shared__ float Qc[36], Rc[9], PCt[18], S[9];
    __shared__ float Mall[T_STEPS * 36];   // all M_t, for the G-product phase
    __shared__ float Gb[2][NCHUNK * 36];
    const int tid = threadIdx.x;

    // ---- phase 0: load params (round-3 verbatim) ----
    if (tid < 36) { sA[tid] = Ag[tid]; sB[tid] = Bg[tid]; sQt[tid] = Qtg[tid]; sP[tid] = cov0[tid]; }
    if (tid < 18) sC[tid] = Cg[tid];
    if (tid < 9)  sRt[tid] = Rtg[tid];
    __syncthreads();

    // ---- phase 1: Qc = Qt Qt^T, Rc = Rt Rt^T ----
    if (tid < 36) {
        int i = tid / 6, j = tid % 6; float s = 0.f;
        #pragma unroll
        for (int k = 0; k < 6; ++k) s += sQt[i*6+k] * sQt[j*6+k];
        Qc[tid] = s;
    } else if (tid < 45) {
        int q = tid - 36, i = q / 3, j = q % 3; float s = 0.f;
        #pragma unroll
        for (int k = 0; k < 3; ++k) s += sRt[i*3+k] * sRt[j*3+k];
        Rc[q] = s;
    }
    __syncthreads();

    // ---- hoist static operands into registers ----
    const int i6 = tid / 6, j6 = tid % 6;
    const int i3 = tid / 3, j3 = tid % 3;
    float Ai[6], Aj[6], Acol[6], Bcol[6], Cst[18], Crow[6], Ca[6], Cb[6];
    float qcv = 0.f, rcv = 0.f;
    if (tid < 36) {
        #pragma unroll
        for (int l = 0; l < 6; ++l) {
            Ai[l] = sA[i6*6+l]; Aj[l] = sA[j6*6+l];
            Acol[l] = sA[l*6+j6]; Bcol[l] = sB[l*6+j6];
        }
        #pragma unroll
        for (int l = 0; l < 18; ++l) Cst[l] = sC[l];
        qcv = Qc[tid];
    }
    if (tid < 18) {
        #pragma unroll
        for (int l = 0; l < 6; ++l) Crow[l] = sC[j3*6+l];
    }
    if (tid >= 36 && tid < 45) {
        int q = tid - 36, a = q / 3, b = q % 3;
        #pragma unroll
        for (int l = 0; l < 6; ++l) { Ca[l] = sC[a*6+l]; Cb[l] = sC[b*6+l]; }
        rcv = Rc[q];
    }

    for (int t = 0; t < T_STEPS; ++t) {
        // ---- stage A: P1 = A P A^T + Qc ----
        if (tid < 36) {
            const float4* P4 = (const float4*)sP;
            float4 q0=P4[0],q1=P4[1],q2=P4[2],q3=P4[3],q4=P4[4],
                   q5=P4[5],q6=P4[6],q7=P4[7],q8=P4[8];
            float Pf[36] = { q0.x,q0.y,q0.z,q0.w, q1.x,q1.y,q1.z,q1.w,
                             q2.x,q2.y,q2.z,q2.w, q3.x,q3.y,q3.z,q3.w,
                             q4.x,q4.y,q4.z,q4.w, q5.x,q5.y,q5.z,q5.w,
                             q6.x,q6.y,q6.z,q6.w, q7.x,q7.y,q7.z,q7.w,
                             q8.x,q8.y,q8.z,q8.w };
            float s = qcv;
            #pragma unroll
            for (int k = 0; k < 6; ++k) {
                float tmp = 0.f;
                #pragma unroll
                for (int l = 0; l < 6; ++l) tmp += Pf[k*6+l] * Aj[l];
                s += Ai[k] * tmp;
            }
            P1[tid] = s;
        }
        __syncthreads();

        // ---- stage B: PCt = P1 C^T ; S = C P1 C^T + Rc ----
        if (tid < 18) {
            const float2* R2 = (const float2*)(P1 + i3 * 6);
            float2 r0 = R2[0], r1 = R2[1], r2 = R2[2];
            float s = r0.x*Crow[0] + r0.y*Crow[1] + r1.x*Crow[2]
                    + r1.y*Crow[3] + r2.x*Crow[4] + r2.y*Crow[5];
            PCt[tid] = s;
        } else if (tid >= 36 && tid < 45) {
            const float4* P4 = (const float4*)P1;
            float4 q0=P4[0],q1=P4[1],q2=P4[2],q3=P4[3],q4=P4[4],
                   q5=P4[5],q6=P4[6],q7=P4[7],q8=P4[8];
            float Pf[36] = { q0.x,q0.y,q0.z,q0.w, q1.x,q1.y,q1.z,q1.w,
                             q2.x,q2.y,q2.z,q2.w, q3.x,q3.y,q3.z,q3.w,
                             q4.x,q4.y,q4.z,q4.w, q5.x,q5.y,q5.z,q5.w,
                             q6.x,q6.y,q6.z,q6.w, q7.x,q7.y,q7.z,q7.w,
                             q8.x,q8.y,q8.z,q8.w };
            float s = rcv;
            #pragma unroll
            for (int l = 0; l < 6; ++l) {
                float tmp = 0.f;
                #pragma unroll
                for (int m = 0; m < 6; ++m) tmp += Pf[l*6+m] * Cb[m];
                s += Ca[l] * tmp;
            }
            S[tid - 36] = s;
        }
        __syncthreads();

        // ---- stage C: per-lane inv(S), K, IKC; M, N, Pnext, stores ----
        if (tid < 36) {
            float a = S[0], b = S[1], c = S[2], d = S[3], e = S[4],
                  f = S[5], g = S[6], h = S[7], i9 = S[8];
            float idet = 1.0f / (a*(e*i9-f*h) - b*(d*i9-f*g) + c*(d*h-e*g));
            float s0 =  (e*i9-f*h)*idet, s1 = -(b*i9-c*h)*idet, s2 =  (b*f-c*e)*idet;
            float s3 = -(d*i9-f*g)*idet, s4 =  (a*i9-c*g)*idet, s5 = -(a*f-c*d)*idet;
            float s6 =  (d*h-e*g)*idet,  s7 = -(a*h-b*g)*idet,  s8 =  (a*e-b*d)*idet;

            float Pi0 = PCt[i6*3+0], Pi1 = PCt[i6*3+1], Pi2 = PCt[i6*3+2];
            float K0 = Pi0*s0 + Pi1*s3 + Pi2*s6;
            float K1 = Pi0*s1 + Pi1*s4 + Pi2*s7;
            float K2 = Pi0*s2 + Pi1*s5 + Pi2*s8;

            float ik[6];
            #pragma unroll
            for (int k = 0; k < 6; ++k)
                ik[k] = ((i6 == k) ? 1.f : 0.f)
                      - (K0*Cst[0*6+k] + K1*Cst[1*6+k] + K2*Cst[2*6+k]);

            float mo = 0.f, no = 0.f, pn = 0.f;
            #pragma unroll
            for (int k = 0; k < 6; ++k) {
                mo += ik[k] * Acol[k];
                no += ik[k] * Bcol[k];
                pn += ik[k] * P1[k*6+j6];
            }

            coef[t*NCOEF + tid]      = mo;
            coef[t*NCOEF + 36 + tid] = no;
            if (j6 < 3)
                coef[t*NCOEF + 72 + i6*3 + j6] = (j6 == 0 ? K0 : (j6 == 1 ? K1 : K2));
            sP[tid] = pn;
            Mall[t*36 + tid] = mo;
        }
        __syncthreads();
    }

    // ---- G-product phase: G_c = M_{c*8+7} ... M_{c*8}, 8 chunks in parallel ----
    if (writeG) {
        const int c = tid / 36, e = tid % 36;
        if (tid < NCHUNK * 36) Gb[0][tid] = Mall[(c*CLEN + 0)*36 + e];
        __syncthreads();
        for (int s = 1; s < CLEN; ++s) {
            const int cur = (s - 1) & 1, nxt = s & 1;
            if (tid < NCHUNK * 36) {
                int i = e / 6, j = e % 6;
                float acc = 0.f;
                #pragma unroll
                for (int k = 0; k < 6; ++k)
                    acc += Mall[(c*CLEN + s)*36 + i*6 + k] * Gb[cur][c*36 + k*6 + j];
                Gb[nxt][tid] = acc;
            }
            __syncthreads();
        }
        if (tid < NCHUNK * 36) Gmat[tid] = Gb[(CLEN - 1) & 1][tid];
    }
}

// ---- pass 1: per-chunk offset vectors g_c[b] (chunk replay from m = 0) ----
__global__ __launch_bounds__(256) void ekf_gpass(
    const float* __restrict__ z, const float* __restrict__ u,
    const float* __restrict__ coef, float* __restrict__ g)
{
    const int c = blockIdx.y;
    const int b = blockIdx.x * 256 + threadIdx.x;

    float m[6] = {0.f, 0.f, 0.f, 0.f, 0.f, 0.f};

    #pragma unroll
    for (int s = 0; s < CLEN; ++s) {
        const int t = c * CLEN + s;
        const float* cf = coef + t * NCOEF;        // uniform -> s_load
        const int base  = t * BATCH + b;

        const float*  zp = z + (size_t)base * 3;
        const float2* up = (const float2*)(u + (size_t)base * 6);
        float zz[3] = { zp[0], zp[1], zp[2] };
        float2 u01 = up[0], u23 = up[1], u45 = up[2];
        float uu[6] = { u01.x, u01.y, u23.x, u23.y, u45.x, u45.y };

        float nm[6];
        #pragma unroll
        for (int i = 0; i < 6; ++i) {               // round-1 accumulation order
            float s2 = 0.f;
            #pragma unroll
            for (int j = 0; j < 6; ++j) s2 += cf[i*6+j] * m[j];
            #pragma unroll
            for (int j = 0; j < 6; ++j) s2 += cf[36 + i*6 + j] * uu[j];
            #pragma unroll
            for (int j = 0; j < 3; ++j) s2 += cf[72 + i*3 + j] * zz[j];
            nm[i] = s2;
        }
        #pragma unroll
        for (int i = 0; i < 6; ++i) m[i] = nm[i];
    }

    float2* gp = (float2*)(g + ((size_t)c * BATCH + b) * 6);
    gp[0] = make_float2(m[0], m[1]);
    gp[1] = make_float2(m[2], m[3]);
    gp[2] = make_float2(m[4], m[5]);
}

// ---- pass 2: boundary scan + chunk replay + output writes ----
__global__ __launch_bounds__(256) void ekf_opass(
    const float* __restrict__ z, const float* __restrict__ u,
    const float* __restrict__ mean0, const float* __restrict__ coef,
    const float* __restrict__ Gmat, const float* __restrict__ g,
    float* __restrict__ out)
{
    const int c = blockIdx.y;
    const int b = blockIdx.x * 256 + threadIdx.x;

    float m[6];
    {
        const float2* mp = (const float2*)(mean0 + (size_t)b * 6);
        float2 a0 = mp[0], a1 = mp[1], a2 = mp[2];
        m[0]=a0.x; m[1]=a0.y; m[2]=a1.x; m[3]=a1.y; m[4]=a2.x; m[5]=a2.y;
    }

    // scan to this chunk's start: bm <- G_cc * bm + g_cc  (trip count uniform)
    for (int cc = 0; cc < c; ++cc) {
        const float* G = Gmat + cc * 36;            // uniform -> s_load
        const float2* gp = (const float2*)(g + ((size_t)cc * BATCH + b) * 6);
        float2 g01 = gp[0], g23 = gp[1], g45 = gp[2];
        float gv[6] = { g01.x, g01.y, g23.x, g23.y, g45.x, g45.y };
        float nm[6];
        #pragma unroll
        for (int i = 0; i < 6; ++i) {
            float s2 = gv[i];
            #pragma unroll
            for (int j = 0; j < 6; ++j) s2 += G[i*6+j] * m[j];
            nm[i] = s2;
        }
        #pragma unroll
        for (int i = 0; i < 6; ++i) m[i] = nm[i];
    }

    // replay chunk c with round-1 arithmetic, writing outputs
    #pragma unroll
    for (int s = 0; s < CLEN; ++s) {
        const int t = c * CLEN + s;
        const float* cf = coef + t * NCOEF;         // uniform -> s_load
        const int base  = t * BATCH + b;

        const float*  zp = z + (size_t)base * 3;
        const float2* up = (const float2*)(u + (size_t)base * 6);
        float zz[3] = { zp[0], zp[1], zp[2] };
        float2 u01 = up[0], u23 = up[1], u45 = up[2];
        float uu[6] = { u01.x, u01.y, u23.x, u23.y, u45.x, u45.y };

        float nm[6];
        #pragma unroll
        for (int i = 0; i < 6; ++i) {
            float s2 = 0.f;
            #pragma unroll
            for (int j = 0; j < 6; ++j) s2 += cf[i*6+j] * m[j];
            #pragma unroll
            for (int j = 0; j < 6; ++j) s2 += cf[36 + i*6 + j] * uu[j];
            #pragma unroll
            for (int j = 0; j < 3; ++j) s2 += cf[72 + i*3 + j] * zz[j];
            nm[i] = s2;
        }

        float2* op = (float2*)(out + (size_t)base * 6);
        op[0] = make_float2(nm[0], nm[1]);
        op[1] = make_float2(nm[2], nm[3]);
        op[2] = make_float2(nm[4], nm[5]);

        #pragma unroll
        for (int i = 0; i < 6; ++i) m[i] = nm[i];
    }
}

// ---- fallback mean kernel (round-3 verbatim, used if ws too small) ----
__global__ __launch_bounds__(128) void ekf_mean(
    const float* __restrict__ z, const float* __restrict__ u,
    const float* __restrict__ mean0, const float* __restrict__ coef,
    float* __restrict__ out)
{
    __shared__ float sc[T_STEPS * NCOEF];
    const int tid = threadIdx.x;
    for (int idx = tid; idx < T_STEPS * NCOEF; idx += 128) sc[idx] = coef[idx];

    const int b = blockIdx.x * 128 + tid;
    float m[6];
    {
        const float2* mp = (const float2*)(mean0 + b * 6);
        float2 a0 = mp[0], a1 = mp[1], a2 = mp[2];
        m[0]=a0.x; m[1]=a0.y; m[2]=a1.x; m[3]=a1.y; m[4]=a2.x; m[5]=a2.y;
    }
    __syncthreads();

    #pragma unroll 2
    for (int t = 0; t < T_STEPS; ++t) {
        const float* cf  = &sc[t * NCOEF];
        const int base   = t * BATCH + b;
        const float*  zp = z + base * 3;
        const float2* up = (const float2*)(u + (size_t)base * 6);

        float zz[3] = { zp[0], zp[1], zp[2] };
        float2 u01 = up[0], u23 = up[1], u45 = up[2];
        float uu[6] = { u01.x, u01.y, u23.x, u23.y, u45.x, u45.y };

        float nm[6];
        #pragma unroll
        for (int i = 0; i < 6; ++i) {
            float s = 0.f;
            #pragma unroll
            for (int j = 0; j < 6; ++j) s += cf[i*6+j] * m[j];
            #pragma unroll
            for (int j = 0; j < 6; ++j) s += cf[36 + i*6 + j] * uu[j];
            #pragma unroll
            for (int j = 0; j < 3; ++j) s += cf[72 + i*3 + j] * zz[j];
            nm[i] = s;
        }

        float2* op = (float2*)(out + (size_t)base * 6);
        op[0] = make_float2(nm[0], nm[1]);
        op[1] = make_float2(nm[2], nm[3]);
        op[2] = make_float2(nm[4], nm[5]);

        #pragma unroll
        for (int i = 0; i < 6; ++i) m[i] = nm[i];
    }
}

extern "C" void kernel_launch(void* const* d_in, const int* in_sizes, int n_in,
                              void* d_out, int out_size, void* d_ws, size_t ws_size,
                              hipStream_t stream) {
    const float* meas  = (const float*)d_in[0];
    const float* useq  = (const float*)d_in[1];
    const float* mean0 = (const float*)d_in[2];
    const float* cov0  = (const float*)d_in[3];
    const float* A     = (const float*)d_in[4];
    const float* Bm    = (const float*)d_in[5];
    const float* Qt    = (const float*)d_in[6];
    const float* C     = (const float*)d_in[7];
    const float* Rt    = (const float*)d_in[8];
    float* out  = (float*)d_out;

    float* coef = (float*)d_ws;                       // 23040 B
    float* Gmat = (float*)((char*)d_ws + G_OFF);      // 1152 B
    float* gvec = (float*)((char*)d_ws + GV_OFF);     // 6.29 MB

    const bool scan_path = (ws_size >= (size_t)WS_NEED);

    ekf_precompute<<<1, 512, 0, stream>>>(cov0, A, Bm, Qt, C, Rt, coef, Gmat,
                                          scan_path ? 1 : 0);
    if (scan_path) {
        dim3 grid(BATCH / 256, NCHUNK);
        ekf_gpass<<<grid, 256, 0, stream>>>(meas, useq, coef, gvec);
        ekf_opass<<<grid, 256, 0, stream>>>(meas, useq, mean0, coef, Gmat, gvec, out);
    } else {
        ekf_mean<<<BATCH / 128, 128, 0, stream>>>(meas, useq, mean0, coef, out);
    }
}

// Round 5
// 190.537 us; speedup vs baseline: 1.3370x; 1.0746x over previous
//
#include <hip/hip_runtime.h>

// ExtendedKalmanFilter: T=64, B=32768, D=6, O=3, U=6.
//
// cov0 is broadcast(0.1*I) and A,Bm,Q,C,R are shared => covariance/gain
// recursion is batch-independent. Kernel 1 (1 wave) runs it once, storing
// per-step affine coefficients  mean_{t+1} = M_t mean_t + N_t u_t + K_t z_t,
// plus chunk-composed transitions G_c = M_{c*8+7}...M_{c*8}.
// Kernels 2/3 solve the linear mean recurrence as a chunked scan (8 chunks
// of 8): gpass computes chunk offsets from m=0; opass scans boundaries and
// replays chunks writing outputs. (Round-4 verbatim; proven.)
//
// Round-5 change (single variable): the Riccati loop in ekf_precompute is
// now SINGLE-WAVE and BARRIER-FREE — all cross-lane exchange via
// v_readlane (static src) / __shfl (variable src) instead of LDS+barrier.
// Round 4 spent ~2400 cyc/step on 3x (LDS round-trip + waitcnt + s_barrier);
// the arithmetic itself is round-3 verbatim (proven absmax 0.0625).
// S is computed as C*(P1 C^T) + R = C*PCt + R, which reproduces round-3's
// quadratic-form accumulation order exactly (round-3's inner tmp == PCt row).

#define T_STEPS 64
#define BATCH   32768
#define NCOEF   90   // per-step: M(36) + N(36) + K(18)
#define NCHUNK  8
#define CLEN    8

#define G_OFF   23040                      // bytes: after coef[64*90]
#define GV_OFF  24192                      // bytes: after Gmat[8*36]
#define WS_NEED (GV_OFF + NCHUNK * BATCH * 6 * 4)

__device__ __forceinline__ float rdlane(float v, int lane) {
    return __int_as_float(__builtin_amdgcn_readlane(__float_as_int(v), lane));
}

__global__ __launch_bounds__(64) void ekf_precompute(
    const float* __restrict__ cov0, const float* __restrict__ Ag,
    const float* __restrict__ Bg,   const float* __restrict__ Qtg,
    const float* __restrict__ Cg,   const float* __restrict__ Rtg,
    float* __restrict__ coef, float* __restrict__ Gmat, int writeG)
{
    __shared__ float sA[36], sB[36], sC[18], sQt[36], sRt[9];
    __shared__ float Qc[36], Rc[9];
    __shared__ float Mall[T_STEPS * 36];   // M_t log for the G-product phase
    const int tid = threadIdx.x;

    // ---- setup (once; LDS + barriers fine) ----
    if (tid < 36) { sA[tid] = Ag[tid]; sB[tid] = Bg[tid]; sQt[tid] = Qtg[tid]; }
    if (tid < 18) sC[tid] = Cg[tid];
    if (tid < 9)  sRt[tid] = Rtg[tid];
    __syncthreads();

    if (tid < 36) {                        // Qc = Qt Qt^T  (round-1 order)
        int i = tid / 6, j = tid % 6; float s = 0.f;
        #pragma unroll
        for (int k = 0; k < 6; ++k) s += sQt[i*6+k] * sQt[j*6+k];
        Qc[tid] = s;
    } else if (tid < 45) {                 // Rc = Rt Rt^T
        int q = tid - 36, i = q / 3, j = q % 3; float s = 0.f;
        #pragma unroll
        for (int k = 0; k < 3; ++k) s += sRt[i*3+k] * sRt[j*3+k];
        Rc[q] = s;
    }
    __syncthreads();

    // ---- hoist static operands into per-lane registers ----
    const int i6 = tid / 6, j6 = tid % 6;      // P/P1-owner coords (tid < 36)
    const int i3 = tid / 3, j3 = tid % 3;      // PCt-owner coords (tid < 18)
    const int qS = (tid >= 36 && tid < 45) ? tid - 36 : 0;   // S-owner coords
    const int sa = qS / 3, sb = qS % 3;

    float Ai[6], Aj[6], Acol[6], Bcol[6], Cst[18], Crow[6], Ca[6];
    float qcv = 0.f, rcv = 0.f;
    #pragma unroll
    for (int l = 0; l < 6; ++l) { Ai[l]=0.f; Aj[l]=0.f; Acol[l]=0.f; Bcol[l]=0.f; Crow[l]=0.f; Ca[l]=0.f; }
    #pragma unroll
    for (int l = 0; l < 18; ++l) Cst[l] = 0.f;

    if (tid < 36) {
        #pragma unroll
        for (int l = 0; l < 6; ++l) {
            Ai[l] = sA[i6*6+l]; Aj[l] = sA[j6*6+l];
            Acol[l] = sA[l*6+j6]; Bcol[l] = sB[l*6+j6];
        }
        #pragma unroll
        for (int l = 0; l < 18; ++l) Cst[l] = sC[l];
        qcv = Qc[tid];
    }
    if (tid < 18) {
        #pragma unroll
        for (int l = 0; l < 6; ++l) Crow[l] = sC[j3*6+l];
    }
    if (tid >= 36 && tid < 45) {
        #pragma unroll
        for (int l = 0; l < 6; ++l) Ca[l] = sC[sa*6+l];
        rcv = Rc[qS];
    }

    float Preg = 0.f;                      // lanes 0..35 own P[i6][j6]
    if (tid < 36) Preg = cov0[tid];
    __syncthreads();                       // Mall/LDS quiesce before loop

    for (int t = 0; t < T_STEPS; ++t) {
        // ---- stage A: P1 = A P A^T + Qc (round-3 order; P via readlane) ----
        float Pf[36];
        #pragma unroll
        for (int e = 0; e < 36; ++e) Pf[e] = rdlane(Preg, e);
        float p1 = qcv;
        #pragma unroll
        for (int k = 0; k < 6; ++k) {
            float tmp = 0.f;
            #pragma unroll
            for (int l = 0; l < 6; ++l) tmp += Pf[k*6+l] * Aj[l];
            p1 += Ai[k] * tmp;
        }

        // ---- stage B1: PCt[i3][j3] = sum_l P1[i3][l] * C[j3][l] (lanes 0..17) ----
        float p1r[6];
        #pragma unroll
        for (int l = 0; l < 6; ++l) p1r[l] = __shfl(p1, i3*6 + l);
        float pct = p1r[0]*Crow[0] + p1r[1]*Crow[1] + p1r[2]*Crow[2]
                  + p1r[3]*Crow[3] + p1r[4]*Crow[4] + p1r[5]*Crow[5];

        // ---- stage B2: S[sa][sb] = Rc + sum_l C[sa][l]*PCt[l][sb] (lanes 36..44) ----
        // identical accumulation to round-3's quadratic form (tmp == PCt row)
        float sv = rcv;
        #pragma unroll
        for (int l = 0; l < 6; ++l) sv += Ca[l] * __shfl(pct, l*3 + sb);

        // ---- stage C: inv(S), K, IKC, M/N/Pnext (round-3 verbatim math) ----
        float a  = rdlane(sv, 36), b  = rdlane(sv, 37), c  = rdlane(sv, 38);
        float d  = rdlane(sv, 39), e  = rdlane(sv, 40), f  = rdlane(sv, 41);
        float g  = rdlane(sv, 42), h  = rdlane(sv, 43), i9 = rdlane(sv, 44);
        float idet = 1.0f / (a*(e*i9-f*h) - b*(d*i9-f*g) + c*(d*h-e*g));
        float s0 =  (e*i9-f*h)*idet, s1 = -(b*i9-c*h)*idet, s2 =  (b*f-c*e)*idet;
        float s3 = -(d*i9-f*g)*idet, s4 =  (a*i9-c*g)*idet, s5 = -(a*f-c*d)*idet;
        float s6 =  (d*h-e*g)*idet,  s7 = -(a*h-b*g)*idet,  s8 =  (a*e-b*d)*idet;

        float Pi0 = __shfl(pct, i6*3 + 0);
        float Pi1 = __shfl(pct, i6*3 + 1);
        float Pi2 = __shfl(pct, i6*3 + 2);
        float K0 = Pi0*s0 + Pi1*s3 + Pi2*s6;
        float K1 = Pi0*s1 + Pi1*s4 + Pi2*s7;
        float K2 = Pi0*s2 + Pi1*s5 + Pi2*s8;

        float ik[6];
        #pragma unroll
        for (int k = 0; k < 6; ++k)
            ik[k] = ((i6 == k) ? 1.f : 0.f)
                  - (K0*Cst[0*6+k] + K1*Cst[1*6+k] + K2*Cst[2*6+k]);

        float p1col[6];
        #pragma unroll
        for (int k = 0; k < 6; ++k) p1col[k] = __shfl(p1, k*6 + j6);

        float mo = 0.f, no = 0.f, pn = 0.f;
        #pragma unroll
        for (int k = 0; k < 6; ++k) {
            mo += ik[k] * Acol[k];
            no += ik[k] * Bcol[k];
            pn += ik[k] * p1col[k];
        }

        if (tid < 36) {
            coef[t*NCOEF + tid]      = mo;
            coef[t*NCOEF + 36 + tid] = no;
            if (j6 < 3)
                coef[t*NCOEF + 72 + i6*3 + j6] = (j6 == 0 ? K0 : (j6 == 1 ? K1 : K2));
            Mall[t*36 + tid] = mo;
        }
        Preg = pn;                          // next P (lanes 0..35 meaningful)
    }
    __syncthreads();                        // drain Mall writes before G phase

    // ---- G-product phase: G_c = M_{c*8+7} ... M_{c*8} (round-4 order) ----
    if (writeG) {
        const int im = (tid < 36) ? i6 : 0;           // clamp LDS index
        for (int cch = 0; cch < NCHUNK; ++cch) {
            float Gv = (tid < 36) ? Mall[(cch*CLEN)*36 + tid] : 0.f;
            for (int s = 1; s < CLEN; ++s) {
                float acc = 0.f;
                #pragma unroll
                for (int k = 0; k < 6; ++k) {
                    float gk = __shfl(Gv, k*6 + j6);
                    acc += Mall[(cch*CLEN + s)*36 + im*6 + k] * gk;
                }
                Gv = acc;
            }
            if (tid < 36) Gmat[cch*36 + tid] = Gv;
        }
    }
}

// ---- pass 1: per-chunk offset vectors g_c[b] (round-4 verbatim) ----
__global__ __launch_bounds__(256) void ekf_gpass(
    const float* __restrict__ z, const float* __restrict__ u,
    const float* __restrict__ coef, float* __restrict__ g)
{
    const int c = blockIdx.y;
    const int b = blockIdx.x * 256 + threadIdx.x;

    float m[6] = {0.f, 0.f, 0.f, 0.f, 0.f, 0.f};

    #pragma unroll
    for (int s = 0; s < CLEN; ++s) {
        const int t = c * CLEN + s;
        const float* cf = coef + t * NCOEF;        // uniform -> s_load
        const int base  = t * BATCH + b;

        const float*  zp = z + (size_t)base * 3;
        const float2* up = (const float2*)(u + (size_t)base * 6);
        float zz[3] = { zp[0], zp[1], zp[2] };
        float2 u01 = up[0], u23 = up[1], u45 = up[2];
        float uu[6] = { u01.x, u01.y, u23.x, u23.y, u45.x, u45.y };

        float nm[6];
        #pragma unroll
        for (int i = 0; i < 6; ++i) {               // round-1 accumulation order
            float s2 = 0.f;
            #pragma unroll
            for (int j = 0; j < 6; ++j) s2 += cf[i*6+j] * m[j];
            #pragma unroll
            for (int j = 0; j < 6; ++j) s2 += cf[36 + i*6 + j] * uu[j];
            #pragma unroll
            for (int j = 0; j < 3; ++j) s2 += cf[72 + i*3 + j] * zz[j];
            nm[i] = s2;
        }
        #pragma unroll
        for (int i = 0; i < 6; ++i) m[i] = nm[i];
    }

    float2* gp = (float2*)(g + ((size_t)c * BATCH + b) * 6);
    gp[0] = make_float2(m[0], m[1]);
    gp[1] = make_float2(m[2], m[3]);
    gp[2] = make_float2(m[4], m[5]);
}

// ---- pass 2: boundary scan + chunk replay + output writes (round-4 verbatim) ----
__global__ __launch_bounds__(256) void ekf_opass(
    const float* __restrict__ z, const float* __restrict__ u,
    const float* __restrict__ mean0, const float* __restrict__ coef,
    const float* __restrict__ Gmat, const float* __restrict__ g,
    float* __restrict__ out)
{
    const int c = blockIdx.y;
    const int b = blockIdx.x * 256 + threadIdx.x;

    float m[6];
    {
        const float2* mp = (const float2*)(mean0 + (size_t)b * 6);
        float2 a0 = mp[0], a1 = mp[1], a2 = mp[2];
        m[0]=a0.x; m[1]=a0.y; m[2]=a1.x; m[3]=a1.y; m[4]=a2.x; m[5]=a2.y;
    }

    for (int cc = 0; cc < c; ++cc) {
        const float* G = Gmat + cc * 36;            // uniform -> s_load
        const float2* gp = (const float2*)(g + ((size_t)cc * BATCH + b) * 6);
        float2 g01 = gp[0], g23 = gp[1], g45 = gp[2];
        float gv[6] = { g01.x, g01.y, g23.x, g23.y, g45.x, g45.y };
        float nm[6];
        #pragma unroll
        for (int i = 0; i < 6; ++i) {
            float s2 = gv[i];
            #pragma unroll
            for (int j = 0; j < 6; ++j) s2 += G[i*6+j] * m[j];
            nm[i] = s2;
        }
        #pragma unroll
        for (int i = 0; i < 6; ++i) m[i] = nm[i];
    }

    #pragma unroll
    for (int s = 0; s < CLEN; ++s) {
        const int t = c * CLEN + s;
        const float* cf = coef + t * NCOEF;         // uniform -> s_load
        const int base  = t * BATCH + b;

        const float*  zp = z + (size_t)base * 3;
        const float2* up = (const float2*)(u + (size_t)base * 6);
        float zz[3] = { zp[0], zp[1], zp[2] };
        float2 u01 = up[0], u23 = up[1], u45 = up[2];
        float uu[6] = { u01.x, u01.y, u23.x, u23.y, u45.x, u45.y };

        float nm[6];
        #pragma unroll
        for (int i = 0; i < 6; ++i) {
            float s2 = 0.f;
            #pragma unroll
            for (int j = 0; j < 6; ++j) s2 += cf[i*6+j] * m[j];
            #pragma unroll
            for (int j = 0; j < 6; ++j) s2 += cf[36 + i*6 + j] * uu[j];
            #pragma unroll
            for (int j = 0; j < 3; ++j) s2 += cf[72 + i*3 + j] * zz[j];
            nm[i] = s2;
        }

        float2* op = (float2*)(out + (size_t)base * 6);
        op[0] = make_float2(nm[0], nm[1]);
        op[1] = make_float2(nm[2], nm[3]);
        op[2] = make_float2(nm[4], nm[5]);

        #pragma unroll
        for (int i = 0; i < 6; ++i) m[i] = nm[i];
    }
}

// ---- fallback mean kernel (round-3 verbatim, used if ws too small) ----
__global__ __launch_bounds__(128) void ekf_mean(
    const float* __restrict__ z, const float* __restrict__ u,
    const float* __restrict__ mean0, const float* __restrict__ coef,
    float* __restrict__ out)
{
    __shared__ float sc[T_STEPS * NCOEF];
    const int tid = threadIdx.x;
    for (int idx = tid; idx < T_STEPS * NCOEF; idx += 128) sc[idx] = coef[idx];

    const int b = blockIdx.x * 128 + tid;
    float m[6];
    {
        const float2* mp = (const float2*)(mean0 + b * 6);
        float2 a0 = mp[0], a1 = mp[1], a2 = mp[2];
        m[0]=a0.x; m[1]=a0.y; m[2]=a1.x; m[3]=a1.y; m[4]=a2.x; m[5]=a2.y;
    }
    __syncthreads();

    #pragma unroll 2
    for (int t = 0; t < T_STEPS; ++t) {
        const float* cf  = &sc[t * NCOEF];
        const int base   = t * BATCH + b;
        const float*  zp = z + base * 3;
        const float2* up = (const float2*)(u + (size_t)base * 6);

        float zz[3] = { zp[0], zp[1], zp[2] };
        float2 u01 = up[0], u23 = up[1], u45 = up[2];
        float uu[6] = { u01.x, u01.y, u23.x, u23.y, u45.x, u45.y };

        float nm[6];
        #pragma unroll
        for (int i = 0; i < 6; ++i) {
            float s = 0.f;
            #pragma unroll
            for (int j = 0; j < 6; ++j) s += cf[i*6+j] * m[j];
            #pragma unroll
            for (int j = 0; j < 6; ++j) s += cf[36 + i*6 + j] * uu[j];
            #pragma unroll
            for (int j = 0; j < 3; ++j) s += cf[72 + i*3 + j] * zz[j];
            nm[i] = s;
        }

        float2* op = (float2*)(out + (size_t)base * 6);
        op[0] = make_float2(nm[0], nm[1]);
        op[1] = make_float2(nm[2], nm[3]);
        op[2] = make_float2(nm[4], nm[5]);

        #pragma unroll
        for (int i = 0; i < 6; ++i) m[i] = nm[i];
    }
}

extern "C" void kernel_launch(void* const* d_in, const int* in_sizes, int n_in,
                              void* d_out, int out_size, void* d_ws, size_t ws_size,
                              hipStream_t stream) {
    const float* meas  = (const float*)d_in[0];
    const float* useq  = (const float*)d_in[1];
    const float* mean0 = (const float*)d_in[2];
    const float* cov0  = (const float*)d_in[3];
    const float* A     = (const float*)d_in[4];
    const float* Bm    = (const float*)d_in[5];
    const float* Qt    = (const float*)d_in[6];
    const float* C     = (const float*)d_in[7];
    const float* Rt    = (const float*)d_in[8];
    float* out  = (float*)d_out;

    float* coef = (float*)d_ws;                       // 23040 B
    float* Gmat = (float*)((char*)d_ws + G_OFF);      // 1152 B
    float* gvec = (float*)((char*)d_ws + GV_OFF);     // 6.29 MB

    const bool scan_path = (ws_size >= (size_t)WS_NEED);

    ekf_precompute<<<1, 64, 0, stream>>>(cov0, A, Bm, Qt, C, Rt, coef, Gmat,
                                         scan_path ? 1 : 0);
    if (scan_path) {
        dim3 grid(BATCH / 256, NCHUNK);
        ekf_gpass<<<grid, 256, 0, stream>>>(meas, useq, coef, gvec);
        ekf_opass<<<grid, 256, 0, stream>>>(meas, useq, mean0, coef, Gmat, gvec, out);
    } else {
        ekf_mean<<<BATCH / 128, 128, 0, stream>>>(meas, useq, mean0, coef, out);
    }
}